// Round 2
// baseline (1170.115 us; speedup 1.0000x reference)
//
#include <hip/hip_runtime.h>

typedef __attribute__((ext_vector_type(8))) short s16x8;
typedef __attribute__((ext_vector_type(4))) short s16x4;
typedef __attribute__((ext_vector_type(4))) float f32x4;
typedef __attribute__((ext_vector_type(4))) unsigned short u16x4;

template<int V> struct IC { static constexpr int v = V; };

__device__ __forceinline__ unsigned short f2bf(float f){
  unsigned u = __float_as_uint(f);
  u += 0x7fffu + ((u >> 16) & 1u);   // RNE
  return (unsigned short)(u >> 16);
}

// x0 [16384,256] f32 -> XT [256,16384] bf16
__global__ void xpose_cvt(const float* __restrict__ src, unsigned short* __restrict__ dst){
  __shared__ float tile[64][65];
  const int R0 = blockIdx.x * 64;
  const int C0 = blockIdx.y * 64;
  const int t = threadIdx.x;
  #pragma unroll
  for (int i = 0; i < 16; ++i){
    int id = i * 256 + t; int r = id >> 6, c = id & 63;
    tile[r][c] = src[(size_t)(R0 + r) * 256 + (C0 + c)];
  }
  __syncthreads();
  #pragma unroll
  for (int i = 0; i < 16; ++i){
    int id = i * 256 + t; int c = id >> 6, r = id & 63;
    dst[(size_t)(C0 + c) * 16384 + (R0 + r)] = f2bf(tile[r][c]);
  }
}

__global__ void cvt_k(const float* __restrict__ src, unsigned short* __restrict__ dst, int n){
  int i = (blockIdx.x * 256 + threadIdx.x) * 4;
  if (i + 3 < n){
    float4 v = *(const float4*)(src + i);
    u16x4 o; o.x = f2bf(v.x); o.y = f2bf(v.y); o.z = f2bf(v.z); o.w = f2bf(v.w);
    *(u16x4*)(dst + i) = o;
  }
}

// C[M,BN] = A[M,K] @ B^T   (B stored [BN,K] bf16, K-contiguous). BM=32, 512 thr.
// AMODE: 0 = A fp32 (convert in-flight), 1 = A bf16, 2 = A bf16 + row gather
// EPI:   0 = bf16 row-major | 1 = bias+relu bf16 TRANSPOSED | 2 = bias+relu bf16 row-major | 3 = bias+relu fp32
// STOREA: also store converted bf16 A tile to Aout (layer-1 fused A conversion)
template<int BN, int AMODE, int EPI, int STOREA>
__global__ __launch_bounds__(512, 4)
void gemm_k(const void* __restrict__ Asrc, const unsigned short* __restrict__ Bsrc,
            const float* __restrict__ bias, const int* __restrict__ gidx,
            void* __restrict__ Cdst, unsigned short* __restrict__ Aout,
            const int M, const int Kd)
{
  constexpr int NF = BN / 64;      // n-frags per wave
  constexpr int BITER = BN / 64;   // B staging iterations
  __shared__ __align__(16) unsigned short Alds[2][32 * 64];
  __shared__ __align__(16) unsigned short Blds[2][BN * 64];

  const int tid  = threadIdx.x;
  const int lane = tid & 63;
  const int wv   = tid >> 6;
  const int wm   = wv >> 2;        // 0..1
  const int wn   = wv & 3;         // 0..3
  const int row0 = blockIdx.x * 32;
  const int fr = lane & 15, fq = lane >> 4;

  const int rA = tid >> 4;         // 0..31 (A staging row)
  const int cA = tid & 15;         // 4-elem chunk along K
  const int rB = tid >> 3;         // 0..63 (B staging row)
  const int cB = tid & 7;          // 8-elem chunk along K

  size_t arow;
  if (AMODE == 2) arow = (size_t)gidx[row0 + rA];
  else            arow = (size_t)(row0 + rA);

  f32x4 acc[NF];
  #pragma unroll
  for (int n = 0; n < NF; ++n) acc[n] = f32x4{0.f, 0.f, 0.f, 0.f};

  float4 aF[2]; s16x4 aB[2]; s16x8 bRg[2][BITER];

  auto loadAB = [&](auto rsc, int k0){
    constexpr int RS = decltype(rsc)::v;
    if constexpr (AMODE == 0)
      aF[RS] = *(const float4*)((const float*)Asrc + arow * (size_t)Kd + (k0 + cA * 4));
    else
      aB[RS] = *(const s16x4*)((const unsigned short*)Asrc + arow * (size_t)Kd + (k0 + cA * 4));
    #pragma unroll
    for (int i = 0; i < BITER; ++i)
      bRg[RS][i] = *(const s16x8*)(Bsrc + (size_t)(rB + i * 64) * Kd + (k0 + cB * 8));
  };

  auto writeAB = [&](auto rsc, int buf, int k0){
    constexpr int RS = decltype(rsc)::v;
    s16x4 w;
    if constexpr (AMODE == 0){
      w[0] = (short)f2bf(aF[RS].x); w[1] = (short)f2bf(aF[RS].y);
      w[2] = (short)f2bf(aF[RS].z); w[3] = (short)f2bf(aF[RS].w);
    } else {
      w = aB[RS];
    }
    *(s16x4*)&Alds[buf][rA * 64 + ((((cA >> 1) ^ (rA & 7)) * 8) + (cA & 1) * 4)] = w;
    if constexpr (STOREA)
      *(s16x4*)&Aout[arow * (size_t)Kd + (k0 + cA * 4)] = w;
    #pragma unroll
    for (int i = 0; i < BITER; ++i){
      int r = rB + i * 64;
      *(s16x8*)&Blds[buf][r * 64 + ((cB ^ (r & 7)) * 8)] = bRg[RS][i];
    }
  };

  auto compute = [&](int buf){
    s16x8 af[2]; s16x8 bfr[NF][2];
    #pragma unroll
    for (int kc = 0; kc < 2; ++kc){
      int row = wm * 16 + fr;
      int c = kc * 4 + fq;
      af[kc] = *(const s16x8*)&Alds[buf][row * 64 + ((c ^ (row & 7)) * 8)];
    }
    #pragma unroll
    for (int n = 0; n < NF; ++n)
      #pragma unroll
      for (int kc = 0; kc < 2; ++kc){
        int col = wn * (BN / 4) + n * 16 + fr;
        int c = kc * 4 + fq;
        bfr[n][kc] = *(const s16x8*)&Blds[buf][col * 64 + ((c ^ (col & 7)) * 8)];
      }
    #pragma unroll
    for (int kc = 0; kc < 2; ++kc)
      #pragma unroll
      for (int n = 0; n < NF; ++n)
        acc[n] = __builtin_amdgcn_mfma_f32_16x16x32_bf16(af[kc], bfr[n][kc], acc[n], 0, 0, 0);
  };

  const int nsteps = Kd / 64;   // always even (>=4)
  loadAB(IC<0>{}, 0);
  loadAB(IC<1>{}, 64);
  writeAB(IC<0>{}, 0, 0);
  __syncthreads();

  for (int s = 0; s < nsteps; s += 2){
    // sub-step parity 0 (global step s): compute lds0(k=s), stage k=s+1 -> lds1, load k=s+2 -> reg0
    if (s + 2 < nsteps) loadAB(IC<0>{}, (s + 2) * 64);
    compute(0);
    if (s + 1 < nsteps) writeAB(IC<1>{}, 1, (s + 1) * 64);
    __syncthreads();
    // sub-step parity 1 (global step s+1)
    if (s + 3 < nsteps) loadAB(IC<1>{}, (s + 3) * 64);
    compute(1);
    if (s + 2 < nsteps) writeAB(IC<0>{}, 0, (s + 2) * 64);
    __syncthreads();
  }

  // epilogue: C frag col = lane&15, row = (lane>>4)*4 + j
  {
    int rowb = row0 + wm * 16 + fq * 4;
    #pragma unroll
    for (int n = 0; n < NF; ++n){
      int col = wn * (BN / 4) + n * 16 + fr;
      f32x4 v = acc[n];
      if constexpr (EPI == 0){
        unsigned short* o = (unsigned short*)Cdst;
        #pragma unroll
        for (int j = 0; j < 4; ++j) o[(size_t)(rowb + j) * BN + col] = f2bf(v[j]);
      } else if constexpr (EPI == 1){
        float b = bias[col];
        u16x4 w;
        #pragma unroll
        for (int j = 0; j < 4; ++j) w[j] = f2bf(fmaxf(v[j] + b, 0.f));
        *(u16x4*)((unsigned short*)Cdst + (size_t)col * M + rowb) = w;
      } else if constexpr (EPI == 2){
        float b = bias[col];
        unsigned short* o = (unsigned short*)Cdst;
        #pragma unroll
        for (int j = 0; j < 4; ++j) o[(size_t)(rowb + j) * BN + col] = f2bf(fmaxf(v[j] + b, 0.f));
      } else {
        float b = bias[col];
        float* o = (float*)Cdst;
        #pragma unroll
        for (int j = 0; j < 4; ++j) o[(size_t)(rowb + j) * BN + col] = fmaxf(v[j] + b, 0.f);
      }
    }
  }
}

// out[i] = softmax(encode[i] @ W2^T + b2), one wave per row
__global__ void mlp2_k(const float* __restrict__ enc, const float* __restrict__ W2,
                       const float* __restrict__ b2, float* __restrict__ out){
  int gw = (int)((blockIdx.x * blockDim.x + threadIdx.x) >> 6);   // global wave = row
  int lane = threadIdx.x & 63;
  if (gw >= 8192) return;
  int c = lane & 15, q = lane >> 4;
  const float* e = enc + (size_t)gw * 128 + q * 32;
  const float* w = W2 + c * 128 + q * 32;
  float s = 0.f;
  #pragma unroll
  for (int k = 0; k < 32; ++k) s += e[k] * w[k];
  s += __shfl_xor(s, 16);
  s += __shfl_xor(s, 32);
  s += b2[c];
  float mx = s;
  #pragma unroll
  for (int d = 1; d < 16; d <<= 1) mx = fmaxf(mx, __shfl_xor(mx, d));
  float ex = __expf(s - mx);
  float sm = ex;
  #pragma unroll
  for (int d = 1; d < 16; d <<= 1) sm += __shfl_xor(sm, d);
  float r = ex / sm;
  if (q == 0) out[(size_t)gw * 16 + c] = r;
}

extern "C" void kernel_launch(void* const* d_in, const int* in_sizes, int n_in,
                              void* d_out, int out_size, void* d_ws, size_t ws_size,
                              hipStream_t stream) {
  const float* A  = (const float*)d_in[0];   // [16384,16384]
  const float* x0 = (const float*)d_in[1];   // [16384,256]
  const float* gw = (const float*)d_in[2];   // [3,256,256]
  const float* gb = (const float*)d_in[3];   // [3,256]
  const float* w1 = (const float*)d_in[4];   // [128,256]
  const float* b1 = (const float*)d_in[5];   // [128]
  const float* w2 = (const float*)d_in[6];   // [16,128]
  const float* b2 = (const float*)d_in[7];   // [16]
  const int*  idx = (const int*)d_in[8];     // [8192]
  float* out = (float*)d_out;

  char* ws = (char*)d_ws;
  unsigned short* Abf = (unsigned short*)ws;                        // 16384^2 bf16 (512 MiB)
  unsigned short* xbT = (unsigned short*)(ws + (512u << 20));       // 256*16384 bf16 (8 MiB)
  unsigned short* t   = (unsigned short*)(ws + (520u << 20));       // 16384*256 bf16 (8 MiB)
  unsigned short* x3b = (unsigned short*)(ws + (528u << 20));       // 16384*256 bf16 (8 MiB)
  unsigned short* wgb = (unsigned short*)(ws + (536u << 20));       // 3*256*256 bf16
  unsigned short* w1b = (unsigned short*)(ws + (536u << 20) + 3 * 65536 * 2); // 128*256 bf16

  xpose_cvt<<<dim3(256, 4), 256, 0, stream>>>(x0, xbT);
  cvt_k<<<192, 256, 0, stream>>>(gw, wgb, 3 * 65536);
  cvt_k<<<32, 256, 0, stream>>>(w1, w1b, 128 * 256);

  // layer 0: t = A @ X  (A fp32 streamed, converted, and persisted as bf16 Abf)
  gemm_k<256, 0, 0, 1><<<512, 512, 0, stream>>>(A, xbT, nullptr, nullptr, t, Abf, 16384, 16384);
  gemm_k<256, 1, 1, 0><<<512, 512, 0, stream>>>(t, wgb + 0 * 65536, gb + 0 * 256, nullptr, xbT, nullptr, 16384, 256);
  // layer 1
  gemm_k<256, 1, 0, 0><<<512, 512, 0, stream>>>(Abf, xbT, nullptr, nullptr, t, nullptr, 16384, 16384);
  gemm_k<256, 1, 1, 0><<<512, 512, 0, stream>>>(t, wgb + 1 * 65536, gb + 1 * 256, nullptr, xbT, nullptr, 16384, 256);
  // layer 2
  gemm_k<256, 1, 0, 0><<<512, 512, 0, stream>>>(Abf, xbT, nullptr, nullptr, t, nullptr, 16384, 16384);
  gemm_k<256, 1, 2, 0><<<512, 512, 0, stream>>>(t, wgb + 2 * 65536, gb + 2 * 256, nullptr, x3b, nullptr, 16384, 256);

  // encode = relu(x3[idx] @ W1^T + b1) -> d_out (fp32)
  gemm_k<128, 2, 3, 0><<<256, 512, 0, stream>>>(x3b, w1b, b1, idx, out, nullptr, 8192, 256);
  // out = softmax(encode @ W2^T + b2)
  mlp2_k<<<2048, 256, 0, stream>>>(out, w2, b2, out + (size_t)8192 * 128);
}

// Round 4
// 844.842 us; speedup vs baseline: 1.3850x; 1.3850x over previous
//
#include <hip/hip_runtime.h>

typedef __attribute__((ext_vector_type(8))) short s16x8;
typedef __attribute__((ext_vector_type(4))) short s16x4;
typedef __attribute__((ext_vector_type(4))) float f32x4;
typedef __attribute__((ext_vector_type(4))) unsigned short u16x4;

template<int V> struct IC { static constexpr int v = V; };

__device__ __forceinline__ unsigned short f2bf(float f){
  unsigned u = __float_as_uint(f);
  u += 0x7fffu + ((u >> 16) & 1u);   // RNE
  return (unsigned short)(u >> 16);
}

// x0 [16384,256] f32 -> XT [256,16384] bf16
__global__ void xpose_cvt(const float* __restrict__ src, unsigned short* __restrict__ dst){
  __shared__ float tile[64][65];
  const int R0 = blockIdx.x * 64;
  const int C0 = blockIdx.y * 64;
  const int t = threadIdx.x;
  #pragma unroll
  for (int i = 0; i < 16; ++i){
    int id = i * 256 + t; int r = id >> 6, c = id & 63;
    tile[r][c] = src[(size_t)(R0 + r) * 256 + (C0 + c)];
  }
  __syncthreads();
  #pragma unroll
  for (int i = 0; i < 16; ++i){
    int id = i * 256 + t; int c = id >> 6, r = id & 63;
    dst[(size_t)(C0 + c) * 16384 + (R0 + r)] = f2bf(tile[r][c]);
  }
}

__global__ void cvt_k(const float* __restrict__ src, unsigned short* __restrict__ dst, int n){
  int i = (blockIdx.x * 256 + threadIdx.x) * 4;
  if (i + 3 < n){
    float4 v = *(const float4*)(src + i);
    u16x4 o; o.x = f2bf(v.x); o.y = f2bf(v.y); o.z = f2bf(v.z); o.w = f2bf(v.w);
    *(u16x4*)(dst + i) = o;
  }
}

// ---------------- Big GEMM: P[kc] = A[16384,16384] @ X^T  (split-K=2) ----------------
// BM=128, BN=256, BK=64, 512 thr, 1 block/CU (96 KiB LDS). Grid = 256.
// blockIdx -> xcd = b&7; kchunk = xcd>>2 (each XCD's B-slice [256 x 8192] stays L2-hot);
// m-block = (xcd&3)*32 + (b>>3).   (bits {b2}->kc, {b1,b0,b7..b3}->mi : bijective)
// AMODE: 0 = A fp32 (convert in-flight, persist bf16 to Aout), 1 = A bf16.
template<int AMODE>
__global__ __launch_bounds__(512, 2)
void gemmA_k(const void* __restrict__ Asrc, const unsigned short* __restrict__ Bsrc,
             float* __restrict__ Pdst, unsigned short* __restrict__ Aout)
{
  __shared__ __align__(16) unsigned short Alds[2][128 * 64];
  __shared__ __align__(16) unsigned short Blds[2][256 * 64];

  const int tid  = threadIdx.x;
  const int lane = tid & 63;
  const int wv   = tid >> 6;
  const int wm   = wv >> 2;        // 0..1 (64 rows each)
  const int wn   = wv & 3;         // 0..3 (64 cols each)
  const int fr = lane & 15, fq = lane >> 4;

  const int b    = blockIdx.x;
  const int xcd  = b & 7;
  const int kc   = xcd >> 2;                   // 0..1
  const int mi   = (xcd & 3) * 32 + (b >> 3);  // 0..127
  const int row0 = mi * 128;
  const int kbase = kc * 8192;

  const int rSt = tid >> 3;        // 0..63 (staging row base)
  const int cSt = tid & 7;         // 16B chunk within 64-elem row

  f32x4 acc[4][4];
  #pragma unroll
  for (int m = 0; m < 4; ++m)
    #pragma unroll
    for (int n = 0; n < 4; ++n)
      acc[m][n] = f32x4{0.f, 0.f, 0.f, 0.f};

  float4 aF[2][2][2]; s16x8 aB[2][2]; s16x8 bRg[2][4];

  auto loadAB = [&](auto rsc, int k0){
    constexpr int RS = decltype(rsc)::v;
    #pragma unroll
    for (int i = 0; i < 2; ++i){
      size_t ar = (size_t)(row0 + rSt + i * 64);
      if constexpr (AMODE == 0){
        const float* p = (const float*)Asrc + ar * 16384 + (k0 + cSt * 8);
        aF[RS][i][0] = *(const float4*)p;
        aF[RS][i][1] = *(const float4*)(p + 4);
      } else {
        aB[RS][i] = *(const s16x8*)((const unsigned short*)Asrc + ar * 16384 + (k0 + cSt * 8));
      }
    }
    #pragma unroll
    for (int i = 0; i < 4; ++i)
      bRg[RS][i] = *(const s16x8*)(Bsrc + (size_t)(rSt + i * 64) * 16384 + (k0 + cSt * 8));
  };

  auto writeAB = [&](auto rsc, int buf, int k0){
    constexpr int RS = decltype(rsc)::v;
    #pragma unroll
    for (int i = 0; i < 2; ++i){
      int row = rSt + i * 64;
      s16x8 w;
      if constexpr (AMODE == 0){
        #pragma unroll
        for (int e = 0; e < 4; ++e){ w[e] = (short)f2bf(aF[RS][i][0][e]); w[e+4] = (short)f2bf(aF[RS][i][1][e]); }
      } else {
        w = aB[RS][i];
      }
      *(s16x8*)&Alds[buf][row * 64 + ((cSt ^ (row & 7)) * 8)] = w;
      if constexpr (AMODE == 0)
        *(s16x8*)&Aout[(size_t)(row0 + row) * 16384 + (k0 + cSt * 8)] = w;
    }
    #pragma unroll
    for (int i = 0; i < 4; ++i){
      int row = rSt + i * 64;
      *(s16x8*)&Blds[buf][row * 64 + ((cSt ^ (row & 7)) * 8)] = bRg[RS][i];
    }
  };

  auto compute = [&](int buf){
    s16x8 af[4][2], bfr[4][2];
    #pragma unroll
    for (int m = 0; m < 4; ++m)
      #pragma unroll
      for (int k = 0; k < 2; ++k){
        int row = wm * 64 + m * 16 + fr;
        int c = k * 4 + fq;
        af[m][k] = *(const s16x8*)&Alds[buf][row * 64 + ((c ^ (row & 7)) * 8)];
      }
    #pragma unroll
    for (int n = 0; n < 4; ++n)
      #pragma unroll
      for (int k = 0; k < 2; ++k){
        int col = wn * 64 + n * 16 + fr;
        int c = k * 4 + fq;
        bfr[n][k] = *(const s16x8*)&Blds[buf][col * 64 + ((c ^ (col & 7)) * 8)];
      }
    #pragma unroll
    for (int k = 0; k < 2; ++k)
      #pragma unroll
      for (int m = 0; m < 4; ++m)
        #pragma unroll
        for (int n = 0; n < 4; ++n)
          acc[m][n] = __builtin_amdgcn_mfma_f32_16x16x32_bf16(af[m][k], bfr[n][k], acc[m][n], 0, 0, 0);
  };

  loadAB(IC<0>{}, kbase);
  loadAB(IC<1>{}, kbase + 64);
  writeAB(IC<0>{}, 0, kbase);
  __syncthreads();

  #pragma unroll 1
  for (int s = 0; s < 128; s += 2){
    if (s + 2 < 128) loadAB(IC<0>{}, kbase + (s + 2) * 64);
    compute(0);
    if (s + 1 < 128) writeAB(IC<1>{}, 1, kbase + (s + 1) * 64);
    __syncthreads();
    if (s + 3 < 128) loadAB(IC<1>{}, kbase + (s + 3) * 64);
    compute(1);
    if (s + 2 < 128) writeAB(IC<0>{}, 0, kbase + (s + 2) * 64);
    __syncthreads();
  }

  // epilogue: fp32 partial store. C frag: col = lane&15, row = (lane>>4)*4 + j
  float* P = Pdst + (size_t)kc * 16384 * 256;
  #pragma unroll
  for (int m = 0; m < 4; ++m){
    int rowb = row0 + wm * 64 + m * 16 + fq * 4;
    #pragma unroll
    for (int n = 0; n < 4; ++n){
      int col = wn * 64 + n * 16 + fr;
      #pragma unroll
      for (int j = 0; j < 4; ++j)
        P[(size_t)(rowb + j) * 256 + col] = acc[m][n][j];
    }
  }
}

// ---------------- Small GEMM: C[M,BN] = A[M,Kd] @ B^T, BM=32 ----------------
// AMODE: 1 = A bf16 | 2 = A bf16 + gather | 3 = A = P0+P1 fp32 pair | 4 = pair + gather
// EPI: 1 = bias+relu bf16 TRANSPOSED | 2 = bias+relu bf16 row-major | 3 = bias+relu fp32
template<int BN, int AMODE, int EPI>
__global__ __launch_bounds__(512, 4)
void gemm_k(const void* __restrict__ Asrc, const unsigned short* __restrict__ Bsrc,
            const float* __restrict__ bias, const int* __restrict__ gidx,
            void* __restrict__ Cdst, const int M, const int Kd)
{
  constexpr int NF = BN / 64;
  constexpr int BITER = BN / 64;
  __shared__ __align__(16) unsigned short Alds[2][32 * 64];
  __shared__ __align__(16) unsigned short Blds[2][BN * 64];

  const int tid  = threadIdx.x;
  const int lane = tid & 63;
  const int wv   = tid >> 6;
  const int wm   = wv >> 2;
  const int wn   = wv & 3;
  const int row0 = blockIdx.x * 32;
  const int fr = lane & 15, fq = lane >> 4;

  const int rA = tid >> 4;         // 0..31
  const int cA = tid & 15;         // 4-elem chunk along K
  const int rB = tid >> 3;         // 0..63
  const int cB = tid & 7;          // 8-elem chunk along K

  size_t arow;
  if (AMODE == 2 || AMODE == 4) arow = (size_t)gidx[row0 + rA];
  else                          arow = (size_t)(row0 + rA);

  const float* P1 = (const float*)Asrc + (size_t)16384 * 256;   // second partial (AMODE 3/4)

  f32x4 acc[NF];
  #pragma unroll
  for (int n = 0; n < NF; ++n) acc[n] = f32x4{0.f, 0.f, 0.f, 0.f};

  float4 aF0[2], aF1[2]; s16x4 aB[2]; s16x8 bRg[2][BITER];

  auto loadAB = [&](auto rsc, int k0){
    constexpr int RS = decltype(rsc)::v;
    if constexpr (AMODE == 3 || AMODE == 4){
      aF0[RS] = *(const float4*)((const float*)Asrc + arow * (size_t)Kd + (k0 + cA * 4));
      aF1[RS] = *(const float4*)(P1 + arow * (size_t)Kd + (k0 + cA * 4));
    } else {
      aB[RS] = *(const s16x4*)((const unsigned short*)Asrc + arow * (size_t)Kd + (k0 + cA * 4));
    }
    #pragma unroll
    for (int i = 0; i < BITER; ++i)
      bRg[RS][i] = *(const s16x8*)(Bsrc + (size_t)(rB + i * 64) * Kd + (k0 + cB * 8));
  };

  auto writeAB = [&](auto rsc, int buf){
    constexpr int RS = decltype(rsc)::v;
    s16x4 w;
    if constexpr (AMODE == 3 || AMODE == 4){
      #pragma unroll
      for (int e = 0; e < 4; ++e) w[e] = (short)f2bf(aF0[RS][e] + aF1[RS][e]);
    } else {
      w = aB[RS];
    }
    *(s16x4*)&Alds[buf][rA * 64 + ((((cA >> 1) ^ (rA & 7)) * 8) + (cA & 1) * 4)] = w;
    #pragma unroll
    for (int i = 0; i < BITER; ++i){
      int r = rB + i * 64;
      *(s16x8*)&Blds[buf][r * 64 + ((cB ^ (r & 7)) * 8)] = bRg[RS][i];
    }
  };

  auto compute = [&](int buf){
    s16x8 af[2]; s16x8 bfr[NF][2];
    #pragma unroll
    for (int k = 0; k < 2; ++k){
      int row = wm * 16 + fr;
      int c = k * 4 + fq;
      af[k] = *(const s16x8*)&Alds[buf][row * 64 + ((c ^ (row & 7)) * 8)];
    }
    #pragma unroll
    for (int n = 0; n < NF; ++n)
      #pragma unroll
      for (int k = 0; k < 2; ++k){
        int col = wn * (BN / 4) + n * 16 + fr;
        int c = k * 4 + fq;
        bfr[n][k] = *(const s16x8*)&Blds[buf][col * 64 + ((c ^ (col & 7)) * 8)];
      }
    #pragma unroll
    for (int k = 0; k < 2; ++k)
      #pragma unroll
      for (int n = 0; n < NF; ++n)
        acc[n] = __builtin_amdgcn_mfma_f32_16x16x32_bf16(af[k], bfr[n][k], acc[n], 0, 0, 0);
  };

  const int nsteps = Kd / 64;
  loadAB(IC<0>{}, 0);
  loadAB(IC<1>{}, 64);
  writeAB(IC<0>{}, 0);
  __syncthreads();

  for (int s = 0; s < nsteps; s += 2){
    if (s + 2 < nsteps) loadAB(IC<0>{}, (s + 2) * 64);
    compute(0);
    if (s + 1 < nsteps) writeAB(IC<1>{}, 1);
    __syncthreads();
    if (s + 3 < nsteps) loadAB(IC<1>{}, (s + 3) * 64);
    compute(1);
    if (s + 2 < nsteps) writeAB(IC<0>{}, 0);
    __syncthreads();
  }

  {
    int rowb = row0 + wm * 16 + fq * 4;
    #pragma unroll
    for (int n = 0; n < NF; ++n){
      int col = wn * (BN / 4) + n * 16 + fr;
      f32x4 v = acc[n];
      float b = bias[col];
      if constexpr (EPI == 1){
        u16x4 w;
        #pragma unroll
        for (int j = 0; j < 4; ++j) w[j] = f2bf(fmaxf(v[j] + b, 0.f));
        *(u16x4*)((unsigned short*)Cdst + (size_t)col * M + rowb) = w;
      } else if constexpr (EPI == 2){
        unsigned short* o = (unsigned short*)Cdst;
        #pragma unroll
        for (int j = 0; j < 4; ++j) o[(size_t)(rowb + j) * BN + col] = f2bf(fmaxf(v[j] + b, 0.f));
      } else {
        float* o = (float*)Cdst;
        #pragma unroll
        for (int j = 0; j < 4; ++j) o[(size_t)(rowb + j) * BN + col] = fmaxf(v[j] + b, 0.f);
      }
    }
  }
}

// out[i] = softmax(encode[i] @ W2^T + b2), one wave per row
__global__ void mlp2_k(const float* __restrict__ enc, const float* __restrict__ W2,
                       const float* __restrict__ b2, float* __restrict__ out){
  int gw = (int)((blockIdx.x * blockDim.x + threadIdx.x) >> 6);
  int lane = threadIdx.x & 63;
  if (gw >= 8192) return;
  int c = lane & 15, q = lane >> 4;
  const float* e = enc + (size_t)gw * 128 + q * 32;
  const float* w = W2 + c * 128 + q * 32;
  float s = 0.f;
  #pragma unroll
  for (int k = 0; k < 32; ++k) s += e[k] * w[k];
  s += __shfl_xor(s, 16);
  s += __shfl_xor(s, 32);
  s += b2[c];
  float mx = s;
  #pragma unroll
  for (int d = 1; d < 16; d <<= 1) mx = fmaxf(mx, __shfl_xor(mx, d));
  float ex = __expf(s - mx);
  float sm = ex;
  #pragma unroll
  for (int d = 1; d < 16; d <<= 1) sm += __shfl_xor(sm, d);
  float r = ex / sm;
  if (q == 0) out[(size_t)gw * 16 + c] = r;
}

extern "C" void kernel_launch(void* const* d_in, const int* in_sizes, int n_in,
                              void* d_out, int out_size, void* d_ws, size_t ws_size,
                              hipStream_t stream) {
  const float* A  = (const float*)d_in[0];   // [16384,16384]
  const float* x0 = (const float*)d_in[1];   // [16384,256]
  const float* gw = (const float*)d_in[2];   // [3,256,256]
  const float* gb = (const float*)d_in[3];   // [3,256]
  const float* w1 = (const float*)d_in[4];   // [128,256]
  const float* b1 = (const float*)d_in[5];   // [128]
  const float* w2 = (const float*)d_in[6];   // [16,128]
  const float* b2 = (const float*)d_in[7];   // [16]
  const int*  idx = (const int*)d_in[8];     // [8192]
  float* out = (float*)d_out;

  char* ws = (char*)d_ws;
  unsigned short* Abf = (unsigned short*)ws;                        // 16384^2 bf16 (512 MiB)
  float*          P   = (float*)(ws + (512u << 20));                // 2 x 16384*256 f32 (32 MiB)
  unsigned short* xbT = (unsigned short*)(ws + (544u << 20));       // 256*16384 bf16 (8 MiB)
  unsigned short* x3b = (unsigned short*)(ws + (552u << 20));       // 16384*256 bf16 (8 MiB)
  unsigned short* wgb = (unsigned short*)(ws + (560u << 20));       // 3*256*256 bf16
  unsigned short* w1b = (unsigned short*)(ws + (560u << 20) + 3 * 65536 * 2); // 128*256 bf16

  xpose_cvt<<<dim3(256, 4), 256, 0, stream>>>(x0, xbT);
  cvt_k<<<192, 256, 0, stream>>>(gw, wgb, 3 * 65536);
  cvt_k<<<32, 256, 0, stream>>>(w1, w1b, 128 * 256);

  // layer 0: P = A @ X (split-K=2, fp32 A converted + persisted to Abf)
  gemmA_k<0><<<256, 512, 0, stream>>>(A, xbT, P, Abf);
  gemm_k<256, 3, 1><<<512, 512, 0, stream>>>(P, wgb + 0 * 65536, gb + 0 * 256, nullptr, xbT, 16384, 256);
  // layer 1
  gemmA_k<1><<<256, 512, 0, stream>>>(Abf, xbT, P, nullptr);
  gemm_k<256, 3, 1><<<512, 512, 0, stream>>>(P, wgb + 1 * 65536, gb + 1 * 256, nullptr, xbT, 16384, 256);
  // layer 2: x3 = relu((P0+P1) @ W_2^T + b_2), row-major bf16
  gemmA_k<1><<<256, 512, 0, stream>>>(Abf, xbT, P, nullptr);
  gemm_k<256, 3, 2><<<512, 512, 0, stream>>>(P, wgb + 2 * 65536, gb + 2 * 256, nullptr, x3b, 16384, 256);
  // encode = relu(x3[idx] @ W1^T + b1) -> d_out fp32
  gemm_k<128, 2, 3><<<256, 512, 0, stream>>>(x3b, w1b, b1, idx, out, 8192, 256);
  // out = softmax(encode @ W2^T + b2)
  mlp2_k<<<2048, 256, 0, stream>>>(out, w2, b2, out + (size_t)8192 * 128);
}

// Round 6
// 837.513 us; speedup vs baseline: 1.3971x; 1.0088x over previous
//
#include <hip/hip_runtime.h>

typedef __attribute__((ext_vector_type(8))) short s16x8;
typedef __attribute__((ext_vector_type(4))) short s16x4;
typedef __attribute__((ext_vector_type(4))) float f32x4;
typedef __attribute__((ext_vector_type(4))) unsigned short u16x4;

template<int V> struct IC { static constexpr int v = V; };

__device__ __forceinline__ unsigned short f2bf(float f){
  unsigned u = __float_as_uint(f);
  u += 0x7fffu + ((u >> 16) & 1u);   // RNE
  return (unsigned short)(u >> 16);
}

// x0 [16384,256] f32 -> XT [256,16384] bf16
__global__ void xpose_cvt(const float* __restrict__ src, unsigned short* __restrict__ dst){
  __shared__ float tile[64][65];
  const int R0 = blockIdx.x * 64;
  const int C0 = blockIdx.y * 64;
  const int t = threadIdx.x;
  #pragma unroll
  for (int i = 0; i < 16; ++i){
    int id = i * 256 + t; int r = id >> 6, c = id & 63;
    tile[r][c] = src[(size_t)(R0 + r) * 256 + (C0 + c)];
  }
  __syncthreads();
  #pragma unroll
  for (int i = 0; i < 16; ++i){
    int id = i * 256 + t; int c = id >> 6, r = id & 63;
    dst[(size_t)(C0 + c) * 16384 + (R0 + r)] = f2bf(tile[r][c]);
  }
}

__global__ void cvt_k(const float* __restrict__ src, unsigned short* __restrict__ dst, int n){
  int i = (blockIdx.x * 256 + threadIdx.x) * 4;
  if (i + 3 < n){
    f32x4 v = *(const f32x4*)(src + i);
    u16x4 o; o[0] = f2bf(v[0]); o[1] = f2bf(v[1]); o[2] = f2bf(v[2]); o[3] = f2bf(v[3]);
    *(u16x4*)(dst + i) = o;
  }
}

// ---------------- Big GEMM: P[kc] = A[16384,16384] @ X^T  (split-K=4) ----------------
// BM=256, BN=256, BK=64, 512 thr (8 waves as 4m x 2n, wave tile 64x128). LDS 128 KiB, 1 blk/CU.
// Grid 256: xcd = b&7; kc = xcd>>1 (per-XCD B-slice 256x4096 bf16 = 2 MiB, L2-resident);
// mi = (xcd&1)*32 + (b>>3)  in [0,64).   A is streamed with non-temporal loads.
// AMODE: 0 = A fp32 (convert in-flight, persist bf16 to Aout), 1 = A bf16.
template<int AMODE>
__global__ __launch_bounds__(512, 2)
void gemmA_k(const void* __restrict__ Asrc, const unsigned short* __restrict__ Bsrc,
             float* __restrict__ Pdst, unsigned short* __restrict__ Aout)
{
  __shared__ __align__(16) unsigned short Alds[2][256 * 64];
  __shared__ __align__(16) unsigned short Blds[2][256 * 64];

  const int tid  = threadIdx.x;
  const int lane = tid & 63;
  const int wv   = tid >> 6;
  const int wm   = wv >> 1;        // 0..3 (64 rows each)
  const int wn   = wv & 1;         // 0..1 (128 cols each)
  const int fr = lane & 15, fq = lane >> 4;

  const int b    = blockIdx.x;
  const int xcd  = b & 7;
  const int kc   = xcd >> 1;                    // 0..3
  const int mi   = ((xcd & 1) << 5) + (b >> 3); // 0..63
  const int row0 = mi * 256;
  const int kbase = kc * 4096;

  const int r8  = tid >> 3, c8  = tid & 7;   // bf16 staging: 8x16B chunks per 64-elem row
  const int r16 = tid >> 4, c16 = tid & 15;  // fp32 staging: 16x16B chunks per row

  f32x4 acc[4][8];
  #pragma unroll
  for (int m = 0; m < 4; ++m)
    #pragma unroll
    for (int n = 0; n < 8; ++n)
      acc[m][n] = f32x4{0.f, 0.f, 0.f, 0.f};

  f32x4 aF[8]; s16x8 aB[4]; s16x8 bR[4];

  auto loadA = [&](int k0){
    if constexpr (AMODE == 0){
      #pragma unroll
      for (int i = 0; i < 8; ++i){
        const float* p = (const float*)Asrc + (size_t)(row0 + i * 32 + r16) * 16384 + (k0 + c16 * 4);
        aF[i] = __builtin_nontemporal_load((const f32x4*)p);
      }
    } else {
      #pragma unroll
      for (int i = 0; i < 4; ++i){
        const unsigned short* p = (const unsigned short*)Asrc + (size_t)(row0 + i * 64 + r8) * 16384 + (k0 + c8 * 8);
        aB[i] = __builtin_nontemporal_load((const s16x8*)p);
      }
    }
  };
  auto loadB = [&](int k0){
    #pragma unroll
    for (int i = 0; i < 4; ++i)
      bR[i] = *(const s16x8*)(Bsrc + (size_t)(i * 64 + r8) * 16384 + (k0 + c8 * 8));
  };

  auto writeAB = [&](int buf, int k0){
    if constexpr (AMODE == 0){
      #pragma unroll
      for (int i = 0; i < 8; ++i){
        int row = i * 32 + r16;
        u16x4 w;
        #pragma unroll
        for (int e = 0; e < 4; ++e) w[e] = f2bf(aF[i][e]);
        *(u16x4*)&Alds[buf][row * 64 + (((c16 >> 1) ^ (row & 7)) * 8) + (c16 & 1) * 4] = w;
        __builtin_nontemporal_store(w, (u16x4*)&Aout[(size_t)(row0 + row) * 16384 + (k0 + c16 * 4)]);
      }
    } else {
      #pragma unroll
      for (int i = 0; i < 4; ++i){
        int row = i * 64 + r8;
        *(s16x8*)&Alds[buf][row * 64 + ((c8 ^ (row & 7)) * 8)] = aB[i];
      }
    }
    #pragma unroll
    for (int i = 0; i < 4; ++i){
      int row = i * 64 + r8;
      *(s16x8*)&Blds[buf][row * 64 + ((c8 ^ (row & 7)) * 8)] = bR[i];
    }
  };

  auto compute = [&](int buf){
    #pragma unroll
    for (int k = 0; k < 2; ++k){
      s16x8 af[4], bfr[8];
      int c = k * 4 + fq;
      #pragma unroll
      for (int m = 0; m < 4; ++m){
        int row = wm * 64 + m * 16 + fr;
        af[m] = *(const s16x8*)&Alds[buf][row * 64 + ((c ^ (row & 7)) * 8)];
      }
      #pragma unroll
      for (int n = 0; n < 8; ++n){
        int col = wn * 128 + n * 16 + fr;
        bfr[n] = *(const s16x8*)&Blds[buf][col * 64 + ((c ^ (col & 7)) * 8)];
      }
      #pragma unroll
      for (int m = 0; m < 4; ++m)
        #pragma unroll
        for (int n = 0; n < 8; ++n)
          acc[m][n] = __builtin_amdgcn_mfma_f32_16x16x32_bf16(af[m], bfr[n], acc[m][n], 0, 0, 0);
    }
  };

  loadB(kbase);
  loadA(kbase);
  writeAB(0, kbase);
  __syncthreads();

  int buf = 0;
  #pragma unroll 1
  for (int s = 0; s < 64; ++s){
    if (s + 1 < 64){ loadB(kbase + (s + 1) * 64); loadA(kbase + (s + 1) * 64); }
    compute(buf);
    if (s + 1 < 64) writeAB(buf ^ 1, kbase + (s + 1) * 64);
    __syncthreads();
    buf ^= 1;
  }

  // epilogue: fp32 partial store (nt). C frag: col = lane&15, row = (lane>>4)*4 + j
  float* P = Pdst + (size_t)kc * 16384 * 256;
  #pragma unroll
  for (int m = 0; m < 4; ++m){
    int rowb = row0 + wm * 64 + m * 16 + fq * 4;
    #pragma unroll
    for (int n = 0; n < 8; ++n){
      int col = wn * 128 + n * 16 + fr;
      #pragma unroll
      for (int j = 0; j < 4; ++j)
        __builtin_nontemporal_store(acc[m][n][j], &P[(size_t)(rowb + j) * 256 + col]);
    }
  }
}

// ---------------- Small GEMM: C[M,BN] = A[M,Kd] @ B^T, BM=32 ----------------
// AMODE: 1 = A bf16 | 2 = A bf16 + gather | 3 = A = sum of 4 fp32 partials
// EPI: 1 = bias+relu bf16 TRANSPOSED | 2 = bias+relu bf16 row-major | 3 = bias+relu fp32
template<int BN, int AMODE, int EPI>
__global__ __launch_bounds__(512, 2)
void gemm_k(const void* __restrict__ Asrc, const unsigned short* __restrict__ Bsrc,
            const float* __restrict__ bias, const int* __restrict__ gidx,
            void* __restrict__ Cdst, const int M, const int Kd)
{
  constexpr int NF = BN / 64;
  constexpr int BITER = BN / 64;
  __shared__ __align__(16) unsigned short Alds[2][32 * 64];
  __shared__ __align__(16) unsigned short Blds[2][BN * 64];

  const int tid  = threadIdx.x;
  const int lane = tid & 63;
  const int wv   = tid >> 6;
  const int wm   = wv >> 2;
  const int wn   = wv & 3;
  const int row0 = blockIdx.x * 32;
  const int fr = lane & 15, fq = lane >> 4;

  const int rA = tid >> 4;         // 0..31
  const int cA = tid & 15;         // 4-elem chunk along K
  const int rB = tid >> 3;         // 0..63
  const int cB = tid & 7;          // 8-elem chunk along K

  size_t arow;
  if (AMODE == 2) arow = (size_t)gidx[row0 + rA];
  else            arow = (size_t)(row0 + rA);

  f32x4 acc[NF];
  #pragma unroll
  for (int n = 0; n < NF; ++n) acc[n] = f32x4{0.f, 0.f, 0.f, 0.f};

  f32x4 aP[2][4]; s16x4 aB[2]; s16x8 bRg[2][BITER];

  auto loadAB = [&](auto rsc, int k0){
    constexpr int RS = decltype(rsc)::v;
    if constexpr (AMODE == 3){
      #pragma unroll
      for (int q = 0; q < 4; ++q)
        aP[RS][q] = __builtin_nontemporal_load(
          (const f32x4*)((const float*)Asrc + (size_t)q * 16384 * 256 + arow * (size_t)Kd + (k0 + cA * 4)));
    } else {
      aB[RS] = *(const s16x4*)((const unsigned short*)Asrc + arow * (size_t)Kd + (k0 + cA * 4));
    }
    #pragma unroll
    for (int i = 0; i < BITER; ++i)
      bRg[RS][i] = *(const s16x8*)(Bsrc + (size_t)(rB + i * 64) * Kd + (k0 + cB * 8));
  };

  auto writeAB = [&](auto rsc, int buf){
    constexpr int RS = decltype(rsc)::v;
    s16x4 w;
    if constexpr (AMODE == 3){
      #pragma unroll
      for (int e = 0; e < 4; ++e)
        w[e] = (short)f2bf(aP[RS][0][e] + aP[RS][1][e] + aP[RS][2][e] + aP[RS][3][e]);
    } else {
      w = aB[RS];
    }
    *(s16x4*)&Alds[buf][rA * 64 + ((((cA >> 1) ^ (rA & 7)) * 8) + (cA & 1) * 4)] = w;
    #pragma unroll
    for (int i = 0; i < BITER; ++i){
      int r = rB + i * 64;
      *(s16x8*)&Blds[buf][r * 64 + ((cB ^ (r & 7)) * 8)] = bRg[RS][i];
    }
  };

  auto compute = [&](int buf){
    s16x8 af[2]; s16x8 bfr[NF][2];
    #pragma unroll
    for (int k = 0; k < 2; ++k){
      int row = wm * 16 + fr;
      int c = k * 4 + fq;
      af[k] = *(const s16x8*)&Alds[buf][row * 64 + ((c ^ (row & 7)) * 8)];
    }
    #pragma unroll
    for (int n = 0; n < NF; ++n)
      #pragma unroll
      for (int k = 0; k < 2; ++k){
        int col = wn * (BN / 4) + n * 16 + fr;
        int c = k * 4 + fq;
        bfr[n][k] = *(const s16x8*)&Blds[buf][col * 64 + ((c ^ (col & 7)) * 8)];
      }
    #pragma unroll
    for (int k = 0; k < 2; ++k)
      #pragma unroll
      for (int n = 0; n < NF; ++n)
        acc[n] = __builtin_amdgcn_mfma_f32_16x16x32_bf16(af[k], bfr[n][k], acc[n], 0, 0, 0);
  };

  const int nsteps = Kd / 64;
  loadAB(IC<0>{}, 0);
  loadAB(IC<1>{}, 64);
  writeAB(IC<0>{}, 0);
  __syncthreads();

  for (int s = 0; s < nsteps; s += 2){
    if (s + 2 < nsteps) loadAB(IC<0>{}, (s + 2) * 64);
    compute(0);
    if (s + 1 < nsteps) writeAB(IC<1>{}, 1);
    __syncthreads();
    if (s + 3 < nsteps) loadAB(IC<1>{}, (s + 3) * 64);
    compute(1);
    if (s + 2 < nsteps) writeAB(IC<0>{}, 0);
    __syncthreads();
  }

  {
    int rowb = row0 + wm * 16 + fq * 4;
    #pragma unroll
    for (int n = 0; n < NF; ++n){
      int col = wn * (BN / 4) + n * 16 + fr;
      f32x4 v = acc[n];
      float b = bias[col];
      if constexpr (EPI == 1){
        u16x4 w;
        #pragma unroll
        for (int j = 0; j < 4; ++j) w[j] = f2bf(fmaxf(v[j] + b, 0.f));
        *(u16x4*)((unsigned short*)Cdst + (size_t)col * M + rowb) = w;
      } else if constexpr (EPI == 2){
        unsigned short* o = (unsigned short*)Cdst;
        #pragma unroll
        for (int j = 0; j < 4; ++j) o[(size_t)(rowb + j) * BN + col] = f2bf(fmaxf(v[j] + b, 0.f));
      } else {
        float* o = (float*)Cdst;
        #pragma unroll
        for (int j = 0; j < 4; ++j) o[(size_t)(rowb + j) * BN + col] = fmaxf(v[j] + b, 0.f);
      }
    }
  }
}

// out[i] = softmax(encode[i] @ W2^T + b2), one wave per row
__global__ void mlp2_k(const float* __restrict__ enc, const float* __restrict__ W2,
                       const float* __restrict__ b2, float* __restrict__ out){
  int gw = (int)((blockIdx.x * blockDim.x + threadIdx.x) >> 6);
  int lane = threadIdx.x & 63;
  if (gw >= 8192) return;
  int c = lane & 15, q = lane >> 4;
  const float* e = enc + (size_t)gw * 128 + q * 32;
  const float* w = W2 + c * 128 + q * 32;
  float s = 0.f;
  #pragma unroll
  for (int k = 0; k < 32; ++k) s += e[k] * w[k];
  s += __shfl_xor(s, 16);
  s += __shfl_xor(s, 32);
  s += b2[c];
  float mx = s;
  #pragma unroll
  for (int d = 1; d < 16; d <<= 1) mx = fmaxf(mx, __shfl_xor(mx, d));
  float ex = __expf(s - mx);
  float sm = ex;
  #pragma unroll
  for (int d = 1; d < 16; d <<= 1) sm += __shfl_xor(sm, d);
  float r = ex / sm;
  if (q == 0) out[(size_t)gw * 16 + c] = r;
}

extern "C" void kernel_launch(void* const* d_in, const int* in_sizes, int n_in,
                              void* d_out, int out_size, void* d_ws, size_t ws_size,
                              hipStream_t stream) {
  const float* A  = (const float*)d_in[0];   // [16384,16384]
  const float* x0 = (const float*)d_in[1];   // [16384,256]
  const float* gw = (const float*)d_in[2];   // [3,256,256]
  const float* gb = (const float*)d_in[3];   // [3,256]
  const float* w1 = (const float*)d_in[4];   // [128,256]
  const float* b1 = (const float*)d_in[5];   // [128]
  const float* w2 = (const float*)d_in[6];   // [16,128]
  const float* b2 = (const float*)d_in[7];   // [16]
  const int*  idx = (const int*)d_in[8];     // [8192]
  float* out = (float*)d_out;

  char* ws = (char*)d_ws;
  unsigned short* Abf = (unsigned short*)ws;                        // 16384^2 bf16 (512 MiB)
  float*          P   = (float*)(ws + (512u << 20));                // 4 x 16384*256 f32 (64 MiB)
  unsigned short* xbT = (unsigned short*)(ws + (576u << 20));       // 256*16384 bf16 (8 MiB)
  unsigned short* x3b = (unsigned short*)(ws + (584u << 20));       // 16384*256 bf16 (8 MiB)
  unsigned short* wgb = (unsigned short*)(ws + (592u << 20));       // 3*256*256 bf16
  unsigned short* w1b = (unsigned short*)(ws + (592u << 20) + 3 * 65536 * 2); // 128*256 bf16

  xpose_cvt<<<dim3(256, 4), 256, 0, stream>>>(x0, xbT);
  cvt_k<<<192, 256, 0, stream>>>(gw, wgb, 3 * 65536);
  cvt_k<<<32, 256, 0, stream>>>(w1, w1b, 128 * 256);

  // layer 0: P = A @ X (split-K=4, fp32 A converted + persisted to Abf)
  gemmA_k<0><<<256, 512, 0, stream>>>(A, xbT, P, Abf);
  gemm_k<256, 3, 1><<<512, 512, 0, stream>>>(P, wgb + 0 * 65536, gb + 0 * 256, nullptr, xbT, 16384, 256);
  // layer 1
  gemmA_k<1><<<256, 512, 0, stream>>>(Abf, xbT, P, nullptr);
  gemm_k<256, 3, 1><<<512, 512, 0, stream>>>(P, wgb + 1 * 65536, gb + 1 * 256, nullptr, xbT, 16384, 256);
  // layer 2: x3 = relu((P0+P1+P2+P3) @ W_2^T + b_2), row-major bf16
  gemmA_k<1><<<256, 512, 0, stream>>>(Abf, xbT, P, nullptr);
  gemm_k<256, 3, 2><<<512, 512, 0, stream>>>(P, wgb + 2 * 65536, gb + 2 * 256, nullptr, x3b, 16384, 256);
  // encode = relu(x3[idx] @ W1^T + b1) -> d_out fp32
  gemm_k<128, 2, 3><<<256, 512, 0, stream>>>(x3b, w1b, b1, idx, out, 8192, 256);
  // out = softmax(encode @ W2^T + b2)
  mlp2_k<<<2048, 256, 0, stream>>>(out, w2, b2, out + (size_t)8192 * 128);
}